// Round 1
// baseline (832.978 us; speedup 1.0000x reference)
//
#include <hip/hip_runtime.h>
#include <math.h>

#define N_IN  128
#define N_HID 64
#define N_OUT 40

// ---------------- degree ----------------
__global__ void deg_count(const int* __restrict__ dst, int E, int* __restrict__ deg) {
    int i = blockIdx.x * blockDim.x + threadIdx.x;
    if (i < E) atomicAdd(&deg[dst[i]], 1);
}

__global__ void dinv_kernel(float* __restrict__ buf, int N) {
    int i = blockIdx.x * blockDim.x + threadIdx.x;
    if (i < N) {
        int d = ((const int*)buf)[i] + 1;   // +1 self-loop
        buf[i] = rsqrtf((float)d);
    }
}

// ---------------- tiled GEMM: H[nrows x NC] = X[nrows x K] @ W[K x NC] ----------------
template<int K, int NC>
__global__ __launch_bounds__(256) void gemm_tiled(const float* __restrict__ X,
                                                  const float* __restrict__ W,
                                                  float* __restrict__ H, int nrows) {
    __shared__ float ws[K][NC];
    __shared__ float xs[32][K + 1];          // +1 pad: kill bank conflicts
    const int t = threadIdx.x;
    for (int i = t; i < K * NC; i += 256) ws[i / NC][i % NC] = W[i];
    const int row0 = blockIdx.x * 32;
    for (int i = t; i < 32 * K; i += 256) {
        int r = i / K, c = i % K;
        int gr = row0 + r;
        xs[r][c] = (gr < nrows) ? X[(long long)gr * K + c] : 0.f;
    }
    __syncthreads();

    const int CPT = NC / 8;                  // cols per thread
    const int row = t >> 3;                  // 0..31
    const int c0  = t & 7;
    float acc[CPT];
#pragma unroll
    for (int j = 0; j < CPT; ++j) acc[j] = 0.f;
#pragma unroll 4
    for (int k = 0; k < K; ++k) {
        float xv = xs[row][k];
#pragma unroll
        for (int j = 0; j < CPT; ++j) acc[j] += xv * ws[k][c0 + j * 8];
    }
    int gr = row0 + row;
    if (gr < nrows) {
#pragma unroll
        for (int j = 0; j < CPT; ++j) H[(long long)gr * NC + c0 + j * 8] = acc[j];
    }
}

// ---------------- edge aggregation: agg[dst] += h[src] * dinv[src]*dinv[dst] ----------------
template<int F>
__global__ void aggregate(const int* __restrict__ src, const int* __restrict__ dst,
                          const float* __restrict__ dinv, const float* __restrict__ h,
                          float* __restrict__ agg, int E) {
    long long tid = (long long)blockIdx.x * blockDim.x + threadIdx.x;
    int lane = (int)(tid & 63);
    long long e = tid >> 6;
    if (e >= E || lane >= F) return;
    int s = src[e], d = dst[e];
    float w = dinv[s] * dinv[d];
    atomicAdd(&agg[(long long)d * F + lane], h[(long long)s * F + lane] * w);
}

// ---------------- layer-1 epilogue: a1 = relu(agg1 + h1*dinv^2 + b1) ----------------
__global__ void act1(const float* __restrict__ h1, const float* __restrict__ agg1,
                     const float* __restrict__ dinv, const float* __restrict__ b1,
                     float* __restrict__ a1, int N) {
    long long i = (long long)blockIdx.x * blockDim.x + threadIdx.x;
    if (i < (long long)N * N_HID) {
        int node = (int)(i >> 6), f = (int)(i & 63);
        float dd = dinv[node];
        float v = agg1[i] + h1[i] * dd * dd + b1[f];
        a1[i] = v > 0.f ? v : 0.f;
    }
}

// ---------------- layer-2 epilogue + log_softmax (one 64-lane wave per node) ----------------
__global__ void final_kernel(const float* __restrict__ h2, const float* __restrict__ dinv,
                             const float* __restrict__ b2, float* __restrict__ out, int N) {
    long long tid = (long long)blockIdx.x * blockDim.x + threadIdx.x;
    int node = (int)(tid >> 6);
    int lane = (int)(tid & 63);
    if (node >= N) return;
    float dd = dinv[node]; dd *= dd;
    float val = 0.f;
    float m = -INFINITY;
    if (lane < N_OUT) {
        long long idx = (long long)node * N_OUT + lane;
        val = out[idx] + h2[idx] * dd + b2[lane];
        m = val;
    }
#pragma unroll
    for (int off = 32; off; off >>= 1) m = fmaxf(m, __shfl_xor(m, off));
    float ex = (lane < N_OUT) ? expf(val - m) : 0.f;
#pragma unroll
    for (int off = 32; off; off >>= 1) ex += __shfl_xor(ex, off);
    if (lane < N_OUT) out[(long long)node * N_OUT + lane] = (val - m) - logf(ex);
}

extern "C" void kernel_launch(void* const* d_in, const int* in_sizes, int n_in,
                              void* d_out, int out_size, void* d_ws, size_t ws_size,
                              hipStream_t stream) {
    const float* x  = (const float*)d_in[0];
    const int*   ei = (const int*)d_in[1];
    const float* W1 = (const float*)d_in[2];
    const float* b1 = (const float*)d_in[3];
    const float* W2 = (const float*)d_in[4];
    const float* b2 = (const float*)d_in[5];
    float* out = (float*)d_out;

    const int N = in_sizes[0] / N_IN;     // 100000
    const int E = in_sizes[1] / 2;        // 1600000
    const int* src = ei;
    const int* dst = ei + E;

    float* dinv = (float*)d_ws;                       // N floats (int deg first)
    float* bufA = dinv + N;                           // N*64 (h1, later h2)
    float* bufB = bufA + (size_t)N * N_HID;           // N*64 (agg1 -> a1)

    hipMemsetAsync(dinv, 0, (size_t)N * sizeof(int), stream);
    hipMemsetAsync(bufB, 0, (size_t)N * N_HID * sizeof(float), stream);
    hipMemsetAsync(out,  0, (size_t)N * N_OUT * sizeof(float), stream);

    deg_count<<<(E + 255) / 256, 256, 0, stream>>>(dst, E, (int*)dinv);
    dinv_kernel<<<(N + 255) / 256, 256, 0, stream>>>(dinv, N);

    // layer 1
    gemm_tiled<N_IN, N_HID><<<(N + 31) / 32, 256, 0, stream>>>(x, W1, bufA, N);
    {
        long long th = (long long)E * 64;
        aggregate<N_HID><<<(int)((th + 255) / 256), 256, 0, stream>>>(src, dst, dinv, bufA, bufB, E);
    }
    {
        long long th = (long long)N * N_HID;
        act1<<<(int)((th + 255) / 256), 256, 0, stream>>>(bufA, bufB, dinv, b1, bufB, N);
    }

    // layer 2
    gemm_tiled<N_HID, N_OUT><<<(N + 31) / 32, 256, 0, stream>>>(bufB, W2, bufA, N);
    {
        long long th = (long long)E * 64;
        aggregate<N_OUT><<<(int)((th + 255) / 256), 256, 0, stream>>>(src, dst, dinv, bufA, out, E);
    }
    {
        long long th = (long long)N * 64;
        final_kernel<<<(int)((th + 255) / 256), 256, 0, stream>>>(bufA, dinv, b2, out, N);
    }
}

// Round 2
// 443.592 us; speedup vs baseline: 1.8778x; 1.8778x over previous
//
#include <hip/hip_runtime.h>
#include <math.h>

#define N_IN  128
#define N_HID 64
#define N_OUT 40

// ---------------- degree ----------------
__global__ void deg_count(const int* __restrict__ dst, int E, int* __restrict__ deg) {
    int i = blockIdx.x * blockDim.x + threadIdx.x;
    if (i < E) atomicAdd(&deg[dst[i]], 1);
}

__global__ void dinv_kernel(const int* __restrict__ deg, float* __restrict__ dinv, int N) {
    int i = blockIdx.x * blockDim.x + threadIdx.x;
    if (i < N) dinv[i] = rsqrtf((float)(deg[i] + 1));   // +1 self-loop
}

// ---------------- exclusive scan over deg -> off (3 kernels) ----------------
__global__ void scan1(const int* __restrict__ deg, int N, int* __restrict__ off,
                      int* __restrict__ bsum) {
    __shared__ int lds[256];
    int i = blockIdx.x * 256 + threadIdx.x;
    int v = (i < N) ? deg[i] : 0;
    lds[threadIdx.x] = v;
    __syncthreads();
    for (int o = 1; o < 256; o <<= 1) {
        int t = (threadIdx.x >= o) ? lds[threadIdx.x - o] : 0;
        __syncthreads();
        lds[threadIdx.x] += t;
        __syncthreads();
    }
    if (i < N) off[i] = lds[threadIdx.x] - v;            // local exclusive
    if (threadIdx.x == 255) bsum[blockIdx.x] = lds[255]; // block total
}

__global__ void scan2(int* __restrict__ bsum, int nb) {
    __shared__ int lds[256];
    int carry = 0;
    for (int base = 0; base < nb; base += 256) {
        int i = base + threadIdx.x;
        int v = (i < nb) ? bsum[i] : 0;
        lds[threadIdx.x] = v;
        __syncthreads();
        for (int o = 1; o < 256; o <<= 1) {
            int t = (threadIdx.x >= o) ? lds[threadIdx.x - o] : 0;
            __syncthreads();
            lds[threadIdx.x] += t;
            __syncthreads();
        }
        if (i < nb) bsum[i] = lds[threadIdx.x] - v + carry;
        int tot = lds[255];
        __syncthreads();
        carry += tot;
    }
}

__global__ void scan3(int* __restrict__ off, const int* __restrict__ bsum,
                      int* __restrict__ cur, int N, int E) {
    int i = blockIdx.x * 256 + threadIdx.x;
    if (i < N) {
        int v = off[i] + bsum[blockIdx.x];
        off[i] = v;
        cur[i] = v;
    }
    if (i == 0) off[N] = E;
}

// ---------------- scatter edges into dst-sorted order ----------------
__global__ void scatter_edges(const int* __restrict__ src, const int* __restrict__ dst,
                              int* __restrict__ cur, int* __restrict__ ssrc, int E) {
    int e = blockIdx.x * blockDim.x + threadIdx.x;
    if (e < E) {
        int p = atomicAdd(&cur[dst[e]], 1);
        ssrc[p] = src[e];
    }
}

// ---------------- tiled GEMM with per-row dinv scaling: H = (X@W) * dinv[row] ------
template<int K, int NC>
__global__ __launch_bounds__(256) void gemm_scaled(const float* __restrict__ X,
                                                   const float* __restrict__ W,
                                                   const float* __restrict__ dinv,
                                                   float* __restrict__ H, int nrows) {
    __shared__ float ws[K][NC];
    __shared__ float xs[32][K + 1];
    const int t = threadIdx.x;
    for (int i = t; i < K * NC; i += 256) ws[i / NC][i % NC] = W[i];
    const int row0 = blockIdx.x * 32;
    for (int i = t; i < 32 * K; i += 256) {
        int r = i / K, c = i % K;
        int gr = row0 + r;
        xs[r][c] = (gr < nrows) ? X[(long long)gr * K + c] : 0.f;
    }
    __syncthreads();

    const int CPT = NC / 8;
    const int row = t >> 3;
    const int c0  = t & 7;
    float acc[CPT];
#pragma unroll
    for (int j = 0; j < CPT; ++j) acc[j] = 0.f;
#pragma unroll 4
    for (int k = 0; k < K; ++k) {
        float xv = xs[row][k];
#pragma unroll
        for (int j = 0; j < CPT; ++j) acc[j] += xv * ws[k][c0 + j * 8];
    }
    int gr = row0 + row;
    if (gr < nrows) {
        float dv = dinv[gr];
#pragma unroll
        for (int j = 0; j < CPT; ++j) H[(long long)gr * NC + c0 + j * 8] = acc[j] * dv;
    }
}

// ---------------- layer-1 aggregation (F=64) + bias + ReLU ----------------
// out[d] = relu( dinv[d] * (sum_{s in in(d)} hs[s] + hs[d]) + b )
__global__ __launch_bounds__(256) void agg_relu(const int* __restrict__ off,
                                                const int* __restrict__ ssrc,
                                                const float* __restrict__ dinv,
                                                const float* __restrict__ hs,
                                                const float* __restrict__ bias,
                                                float* __restrict__ outp, int N) {
    int node = blockIdx.x * 4 + (threadIdx.x >> 6);
    int lane = threadIdx.x & 63;
    if (node >= N) return;
    int start = off[node], end = off[node + 1];
    float acc = 0.f;
    for (int j = start; j < end; j += 64) {
        int idx = j + lane;
        int sidx = (idx < end) ? ssrc[idx] : 0;
        int cnt = min(64, end - j);
        int t = 0;
        for (; t + 3 < cnt; t += 4) {
            int s0 = __shfl(sidx, t);
            int s1 = __shfl(sidx, t + 1);
            int s2 = __shfl(sidx, t + 2);
            int s3 = __shfl(sidx, t + 3);
            float v0 = hs[(long long)s0 * 64 + lane];
            float v1 = hs[(long long)s1 * 64 + lane];
            float v2 = hs[(long long)s2 * 64 + lane];
            float v3 = hs[(long long)s3 * 64 + lane];
            acc += v0; acc += v1; acc += v2; acc += v3;
        }
        for (; t < cnt; ++t) {
            int s = __shfl(sidx, t);
            acc += hs[(long long)s * 64 + lane];
        }
    }
    float dd = dinv[node];
    acc = (acc + hs[(long long)node * 64 + lane]) * dd + bias[lane];
    outp[(long long)node * 64 + lane] = fmaxf(acc, 0.f);
}

// ---------------- layer-2 aggregation (F=40) + bias + log_softmax ----------------
__global__ __launch_bounds__(256) void agg_lsm(const int* __restrict__ off,
                                               const int* __restrict__ ssrc,
                                               const float* __restrict__ dinv,
                                               const float* __restrict__ hs,
                                               const float* __restrict__ bias,
                                               float* __restrict__ outp, int N) {
    int node = blockIdx.x * 4 + (threadIdx.x >> 6);
    int lane = threadIdx.x & 63;
    if (node >= N) return;
    int start = off[node], end = off[node + 1];
    float acc = 0.f;
    bool act = lane < N_OUT;
    for (int j = start; j < end; j += 64) {
        int idx = j + lane;
        int sidx = (idx < end) ? ssrc[idx] : 0;
        int cnt = min(64, end - j);
        int t = 0;
        for (; t + 3 < cnt; t += 4) {
            int s0 = __shfl(sidx, t);
            int s1 = __shfl(sidx, t + 1);
            int s2 = __shfl(sidx, t + 2);
            int s3 = __shfl(sidx, t + 3);
            if (act) {
                acc += hs[(long long)s0 * N_OUT + lane];
                acc += hs[(long long)s1 * N_OUT + lane];
                acc += hs[(long long)s2 * N_OUT + lane];
                acc += hs[(long long)s3 * N_OUT + lane];
            }
        }
        for (; t < cnt; ++t) {
            int s = __shfl(sidx, t);
            if (act) acc += hs[(long long)s * N_OUT + lane];
        }
    }
    float val = 0.f, m = -INFINITY;
    if (act) {
        float dd = dinv[node];
        val = (acc + hs[(long long)node * N_OUT + lane]) * dd + bias[lane];
        m = val;
    }
#pragma unroll
    for (int o = 32; o; o >>= 1) m = fmaxf(m, __shfl_xor(m, o));
    float ex = act ? expf(val - m) : 0.f;
#pragma unroll
    for (int o = 32; o; o >>= 1) ex += __shfl_xor(ex, o);
    if (act) outp[(long long)node * N_OUT + lane] = (val - m) - logf(ex);
}

extern "C" void kernel_launch(void* const* d_in, const int* in_sizes, int n_in,
                              void* d_out, int out_size, void* d_ws, size_t ws_size,
                              hipStream_t stream) {
    const float* x  = (const float*)d_in[0];
    const int*   ei = (const int*)d_in[1];
    const float* W1 = (const float*)d_in[2];
    const float* b1 = (const float*)d_in[3];
    const float* W2 = (const float*)d_in[4];
    const float* b2 = (const float*)d_in[5];
    float* out = (float*)d_out;

    const int N = in_sizes[0] / N_IN;     // 100000
    const int E = in_sizes[1] / 2;        // 1600000
    const int* src = ei;
    const int* dst = ei + E;
    const int NB = (N + 255) / 256;       // scan blocks

    // workspace layout
    int*   deg   = (int*)d_ws;                          // N
    int*   off   = deg + N;                             // N+1
    int*   cur   = off + N + 1;                         // N
    int*   bsum  = cur + N;                             // NB
    float* dinv  = (float*)(bsum + NB);                 // N
    int*   ssrc  = (int*)(dinv + N);                    // E
    float* bufA  = (float*)(ssrc + E);                  // N*64
    float* bufB  = bufA + (size_t)N * N_HID;            // N*64

    hipMemsetAsync(deg, 0, (size_t)N * sizeof(int), stream);

    // degree + dinv + CSR offsets + dst-sorted edge list
    deg_count<<<(E + 255) / 256, 256, 0, stream>>>(dst, E, deg);
    dinv_kernel<<<NB, 256, 0, stream>>>(deg, dinv, N);
    scan1<<<NB, 256, 0, stream>>>(deg, N, off, bsum);
    scan2<<<1, 256, 0, stream>>>(bsum, NB);
    scan3<<<NB, 256, 0, stream>>>(off, bsum, cur, N, E);
    scatter_edges<<<(E + 255) / 256, 256, 0, stream>>>(src, dst, cur, ssrc, E);

    // layer 1: hs1 = (x@W1)*dinv  -> agg+bias+relu -> bufB
    gemm_scaled<N_IN, N_HID><<<(N + 31) / 32, 256, 0, stream>>>(x, W1, dinv, bufA, N);
    agg_relu<<<(N + 3) / 4, 256, 0, stream>>>(off, ssrc, dinv, bufA, b1, bufB, N);

    // layer 2: hs2 = (a1@W2)*dinv -> agg+bias+log_softmax -> out
    gemm_scaled<N_HID, N_OUT><<<(N + 31) / 32, 256, 0, stream>>>(bufB, W2, dinv, bufA, N);
    agg_lsm<<<(N + 3) / 4, 256, 0, stream>>>(off, ssrc, dinv, bufA, b2, out, N);
}

// Round 3
// 315.813 us; speedup vs baseline: 2.6376x; 1.4046x over previous
//
#include <hip/hip_runtime.h>
#include <math.h>

#define N_IN  128
#define N_HID 64
#define N_OUT 40

#define BSH   9
#define SZB   512          // nodes per bucket
#define MAXBK 256          // >= NBK (N<=131072)
#define CAP   9216         // LDS staging capacity per bucket (mean 8192, sigma 90)

// ---------------- pass A: global bucket histogram ----------------
__global__ __launch_bounds__(256) void bucket_hist(const int* __restrict__ dst, int E, int NBK,
                                                   int* __restrict__ bcnt) {
    __shared__ int h[MAXBK];
    for (int i = threadIdx.x; i < MAXBK; i += 256) h[i] = 0;
    __syncthreads();
    for (long long i = (long long)blockIdx.x * 256 + threadIdx.x; i < E;
         i += (long long)gridDim.x * 256)
        atomicAdd(&h[dst[i] >> BSH], 1);
    __syncthreads();
    for (int i = threadIdx.x; i < NBK; i += 256)
        if (h[i]) atomicAdd(&bcnt[i], h[i]);
}

// ---------------- pass B: scan bucket counts ----------------
__global__ __launch_bounds__(256) void bucket_scan(const int* __restrict__ bcnt, int NBK, int E,
                                                   int* __restrict__ bbase, int* __restrict__ bcur) {
    __shared__ int lds[MAXBK];
    int t = threadIdx.x;
    int v = (t < NBK) ? bcnt[t] : 0;
    lds[t] = v;
    __syncthreads();
    for (int o = 1; o < 256; o <<= 1) {
        int p = (t >= o) ? lds[t - o] : 0;
        __syncthreads();
        lds[t] += p;
        __syncthreads();
    }
    int ex = lds[t] - v;
    if (t < NBK) { bbase[t] = ex; bcur[t] = ex; }
    if (t == 0) bbase[NBK] = E;
}

// ---------------- pass C: scatter edges into bucket regions (packed) ----------------
__global__ __launch_bounds__(256) void bucket_scatter(const int* __restrict__ src,
                                                      const int* __restrict__ dst,
                                                      int E, int NBK,
                                                      int* __restrict__ bcur,
                                                      int* __restrict__ ebuf) {
    __shared__ int h[MAXBK];
    __shared__ int base[MAXBK];
    int chunk = (E + gridDim.x - 1) / gridDim.x;
    int s = blockIdx.x * chunk;
    int e = min(E, s + chunk);
    for (int i = threadIdx.x; i < MAXBK; i += 256) h[i] = 0;
    __syncthreads();
    for (int i = s + threadIdx.x; i < e; i += 256)
        atomicAdd(&h[dst[i] >> BSH], 1);
    __syncthreads();
    for (int i = threadIdx.x; i < NBK; i += 256) {
        int c = h[i];
        base[i] = c ? atomicAdd(&bcur[i], c) : 0;
    }
    __syncthreads();
    for (int i = threadIdx.x; i < MAXBK; i += 256) h[i] = 0;
    __syncthreads();
    for (int i = s + threadIdx.x; i < e; i += 256) {
        int d = dst[i];
        int b = d >> BSH;
        int lp = atomicAdd(&h[b], 1);
        ebuf[base[b] + lp] = (src[i] << BSH) | (d & (SZB - 1));
    }
}

// ---------------- pass D: per-bucket finalize: deg->dinv, offsets, sorted ssrc ----------------
__global__ __launch_bounds__(256) void bucket_finalize(const int* __restrict__ bbase,
                                                       const int* __restrict__ ebuf,
                                                       int N, int E,
                                                       int* __restrict__ off,
                                                       float* __restrict__ dinv,
                                                       int* __restrict__ ssrc) {
    __shared__ int deg[SZB];
    __shared__ int scn[SZB];
    __shared__ int cur[SZB];
    __shared__ int wsum[256];
    __shared__ int sstage[CAP];
    const int b = blockIdx.x;
    const int s0 = bbase[b], s1 = bbase[b + 1];
    const int cnt = s1 - s0;
    const int n0 = b << BSH;
    const int nn = min(SZB, N - n0);
    const int t = threadIdx.x;
    deg[t] = 0; deg[t + 256] = 0;
    __syncthreads();
    for (int i = s0 + t; i < s1; i += 256)
        atomicAdd(&deg[ebuf[i] & (SZB - 1)], 1);
    __syncthreads();
    // exclusive scan of 512 via 256 pair-sums
    int a0 = deg[2 * t], a1 = deg[2 * t + 1];
    int v = a0 + a1;
    wsum[t] = v;
    __syncthreads();
    for (int o = 1; o < 256; o <<= 1) {
        int p = (t >= o) ? wsum[t - o] : 0;
        __syncthreads();
        wsum[t] += p;
        __syncthreads();
    }
    int ex = wsum[t] - v;
    scn[2 * t] = ex;       scn[2 * t + 1] = ex + a0;
    cur[2 * t] = ex;       cur[2 * t + 1] = ex + a0;
    __syncthreads();
    for (int i = t; i < nn; i += 256) {
        off[n0 + i]  = s0 + scn[i];
        dinv[n0 + i] = rsqrtf((float)(deg[i] + 1));
    }
    if (b == 0 && t == 0) off[N] = E;
    if (cnt <= CAP) {
        for (int i = s0 + t; i < s1; i += 256) {
            int p = ebuf[i];
            int lp = atomicAdd(&cur[p & (SZB - 1)], 1);
            sstage[lp] = p >> BSH;
        }
        __syncthreads();
        for (int i = t; i < cnt; i += 256) ssrc[s0 + i] = sstage[i];
    } else {               // correctness fallback (statistically unreachable)
        for (int i = s0 + t; i < s1; i += 256) {
            int p = ebuf[i];
            int lp = atomicAdd(&cur[p & (SZB - 1)], 1);
            ssrc[s0 + lp] = p >> BSH;
        }
    }
}

// ---------------- tiled GEMM with per-row dinv scaling: H = (X@W) * dinv[row] ------
template<int K, int NC>
__global__ __launch_bounds__(256) void gemm_scaled(const float* __restrict__ X,
                                                   const float* __restrict__ W,
                                                   const float* __restrict__ dinv,
                                                   float* __restrict__ H, int nrows) {
    __shared__ float ws[K][NC];
    __shared__ float xs[32][K + 1];
    const int t = threadIdx.x;
    for (int i = t; i < K * NC; i += 256) ws[i / NC][i % NC] = W[i];
    const int row0 = blockIdx.x * 32;
    for (int i = t; i < 32 * K; i += 256) {
        int r = i / K, c = i % K;
        int gr = row0 + r;
        xs[r][c] = (gr < nrows) ? X[(long long)gr * K + c] : 0.f;
    }
    __syncthreads();

    const int CPT = NC / 8;
    const int row = t >> 3;
    const int c0  = t & 7;
    float acc[CPT];
#pragma unroll
    for (int j = 0; j < CPT; ++j) acc[j] = 0.f;
#pragma unroll 4
    for (int k = 0; k < K; ++k) {
        float xv = xs[row][k];
#pragma unroll
        for (int j = 0; j < CPT; ++j) acc[j] += xv * ws[k][c0 + j * 8];
    }
    int gr = row0 + row;
    if (gr < nrows) {
        float dv = dinv[gr];
#pragma unroll
        for (int j = 0; j < CPT; ++j) H[(long long)gr * NC + c0 + j * 8] = acc[j] * dv;
    }
}

// ---------------- layer-1 aggregation (F=64) + bias + ReLU ----------------
__global__ __launch_bounds__(256) void agg_relu(const int* __restrict__ off,
                                                const int* __restrict__ ssrc,
                                                const float* __restrict__ dinv,
                                                const float* __restrict__ hs,
                                                const float* __restrict__ bias,
                                                float* __restrict__ outp, int N) {
    int node = blockIdx.x * 4 + (threadIdx.x >> 6);
    int lane = threadIdx.x & 63;
    if (node >= N) return;
    int start = off[node], end = off[node + 1];
    float acc = 0.f;
    for (int j = start; j < end; j += 64) {
        int idx = j + lane;
        int sidx = (idx < end) ? ssrc[idx] : 0;
        int cnt = min(64, end - j);
        int t = 0;
        for (; t + 3 < cnt; t += 4) {
            int s0 = __shfl(sidx, t);
            int s1 = __shfl(sidx, t + 1);
            int s2 = __shfl(sidx, t + 2);
            int s3 = __shfl(sidx, t + 3);
            acc += hs[(long long)s0 * 64 + lane];
            acc += hs[(long long)s1 * 64 + lane];
            acc += hs[(long long)s2 * 64 + lane];
            acc += hs[(long long)s3 * 64 + lane];
        }
        for (; t < cnt; ++t) {
            int s = __shfl(sidx, t);
            acc += hs[(long long)s * 64 + lane];
        }
    }
    float dd = dinv[node];
    acc = (acc + hs[(long long)node * 64 + lane]) * dd + bias[lane];
    outp[(long long)node * 64 + lane] = fmaxf(acc, 0.f);
}

// ---------------- layer-2 aggregation (F=40) + bias + log_softmax ----------------
__global__ __launch_bounds__(256) void agg_lsm(const int* __restrict__ off,
                                               const int* __restrict__ ssrc,
                                               const float* __restrict__ dinv,
                                               const float* __restrict__ hs,
                                               const float* __restrict__ bias,
                                               float* __restrict__ outp, int N) {
    int node = blockIdx.x * 4 + (threadIdx.x >> 6);
    int lane = threadIdx.x & 63;
    if (node >= N) return;
    int start = off[node], end = off[node + 1];
    float acc = 0.f;
    bool act = lane < N_OUT;
    for (int j = start; j < end; j += 64) {
        int idx = j + lane;
        int sidx = (idx < end) ? ssrc[idx] : 0;
        int cnt = min(64, end - j);
        int t = 0;
        for (; t + 3 < cnt; t += 4) {
            int s0 = __shfl(sidx, t);
            int s1 = __shfl(sidx, t + 1);
            int s2 = __shfl(sidx, t + 2);
            int s3 = __shfl(sidx, t + 3);
            if (act) {
                acc += hs[(long long)s0 * N_OUT + lane];
                acc += hs[(long long)s1 * N_OUT + lane];
                acc += hs[(long long)s2 * N_OUT + lane];
                acc += hs[(long long)s3 * N_OUT + lane];
            }
        }
        for (; t < cnt; ++t) {
            int s = __shfl(sidx, t);
            if (act) acc += hs[(long long)s * N_OUT + lane];
        }
    }
    float val = 0.f, m = -INFINITY;
    if (act) {
        float dd = dinv[node];
        val = (acc + hs[(long long)node * N_OUT + lane]) * dd + bias[lane];
        m = val;
    }
#pragma unroll
    for (int o = 32; o; o >>= 1) m = fmaxf(m, __shfl_xor(m, o));
    float ex = act ? expf(val - m) : 0.f;
#pragma unroll
    for (int o = 32; o; o >>= 1) ex += __shfl_xor(ex, o);
    if (act) outp[(long long)node * N_OUT + lane] = (val - m) - logf(ex);
}

extern "C" void kernel_launch(void* const* d_in, const int* in_sizes, int n_in,
                              void* d_out, int out_size, void* d_ws, size_t ws_size,
                              hipStream_t stream) {
    const float* x  = (const float*)d_in[0];
    const int*   ei = (const int*)d_in[1];
    const float* W1 = (const float*)d_in[2];
    const float* b1 = (const float*)d_in[3];
    const float* W2 = (const float*)d_in[4];
    const float* b2 = (const float*)d_in[5];
    float* out = (float*)d_out;

    const int N = in_sizes[0] / N_IN;     // 100000
    const int E = in_sizes[1] / 2;        // 1600000
    const int* src = ei;
    const int* dst = ei + E;
    const int NBK = (N + SZB - 1) >> BSH; // 196

    // workspace layout
    int*   bcnt  = (int*)d_ws;                          // MAXBK
    int*   bbase = bcnt + MAXBK;                        // MAXBK+1
    int*   bcur  = bbase + MAXBK + 1;                   // MAXBK
    int*   off   = bcur + MAXBK;                        // N+1
    float* dinv  = (float*)(off + N + 1);               // N
    int*   ssrc  = (int*)(dinv + N);                    // E
    float* bufA  = (float*)(ssrc + E);                  // N*64
    float* bufB  = bufA + (size_t)N * N_HID;            // N*64
    int*   ebuf  = (int*)bufB;                          // E ints, aliases bufB (dead by then)

    hipMemsetAsync(bcnt, 0, MAXBK * sizeof(int), stream);

    // CSR build (bucketed counting sort)
    bucket_hist<<<256, 256, 0, stream>>>(dst, E, NBK, bcnt);
    bucket_scan<<<1, 256, 0, stream>>>(bcnt, NBK, E, bbase, bcur);
    bucket_scatter<<<512, 256, 0, stream>>>(src, dst, E, NBK, bcur, ebuf);
    bucket_finalize<<<NBK, 256, 0, stream>>>(bbase, ebuf, N, E, off, dinv, ssrc);

    // layer 1: hs1 = (x@W1)*dinv  -> agg+bias+relu -> bufB
    gemm_scaled<N_IN, N_HID><<<(N + 31) / 32, 256, 0, stream>>>(x, W1, dinv, bufA, N);
    agg_relu<<<(N + 3) / 4, 256, 0, stream>>>(off, ssrc, dinv, bufA, b1, bufB, N);

    // layer 2: hs2 = (a1@W2)*dinv -> agg+bias+log_softmax -> out
    gemm_scaled<N_HID, N_OUT><<<(N + 31) / 32, 256, 0, stream>>>(bufB, W2, dinv, bufA, N);
    agg_lsm<<<(N + 3) / 4, 256, 0, stream>>>(off, ssrc, dinv, bufA, b2, out, N);
}

// Round 4
// 268.821 us; speedup vs baseline: 3.0986x; 1.1748x over previous
//
#include <hip/hip_runtime.h>
#include <math.h>

#define N_IN  128
#define N_HID 64
#define N_OUT 40

#define BSH   9
#define SZB   512          // nodes per bucket
#define MAXBK 256          // >= NBK (N<=131072)
#define CAP   9216         // LDS staging capacity per bucket (mean 8192, sigma 90)

// ---------------- pass A: global bucket histogram ----------------
__global__ __launch_bounds__(256) void bucket_hist(const int* __restrict__ dst, int E, int NBK,
                                                   int* __restrict__ bcnt) {
    __shared__ int h[MAXBK];
    for (int i = threadIdx.x; i < MAXBK; i += 256) h[i] = 0;
    __syncthreads();
    for (long long i = (long long)blockIdx.x * 256 + threadIdx.x; i < E;
         i += (long long)gridDim.x * 256)
        atomicAdd(&h[dst[i] >> BSH], 1);
    __syncthreads();
    for (int i = threadIdx.x; i < NBK; i += 256)
        if (h[i]) atomicAdd(&bcnt[i], h[i]);
}

// ---------------- pass B: scan bucket counts ----------------
__global__ __launch_bounds__(256) void bucket_scan(const int* __restrict__ bcnt, int NBK, int E,
                                                   int* __restrict__ bbase, int* __restrict__ bcur) {
    __shared__ int lds[MAXBK];
    int t = threadIdx.x;
    int v = (t < NBK) ? bcnt[t] : 0;
    lds[t] = v;
    __syncthreads();
    for (int o = 1; o < 256; o <<= 1) {
        int p = (t >= o) ? lds[t - o] : 0;
        __syncthreads();
        lds[t] += p;
        __syncthreads();
    }
    int ex = lds[t] - v;
    if (t < NBK) { bbase[t] = ex; bcur[t] = ex; }
    if (t == 0) bbase[NBK] = E;
}

// ---------------- pass C: scatter edges into bucket regions (packed) ----------------
__global__ __launch_bounds__(256) void bucket_scatter(const int* __restrict__ src,
                                                      const int* __restrict__ dst,
                                                      int E, int NBK,
                                                      int* __restrict__ bcur,
                                                      int* __restrict__ ebuf) {
    __shared__ int h[MAXBK];
    __shared__ int base[MAXBK];
    int chunk = (E + gridDim.x - 1) / gridDim.x;
    int s = blockIdx.x * chunk;
    int e = min(E, s + chunk);
    for (int i = threadIdx.x; i < MAXBK; i += 256) h[i] = 0;
    __syncthreads();
    for (int i = s + threadIdx.x; i < e; i += 256)
        atomicAdd(&h[dst[i] >> BSH], 1);
    __syncthreads();
    for (int i = threadIdx.x; i < NBK; i += 256) {
        int c = h[i];
        base[i] = c ? atomicAdd(&bcur[i], c) : 0;
    }
    __syncthreads();
    for (int i = threadIdx.x; i < MAXBK; i += 256) h[i] = 0;
    __syncthreads();
    for (int i = s + threadIdx.x; i < e; i += 256) {
        int d = dst[i];
        int b = d >> BSH;
        int lp = atomicAdd(&h[b], 1);
        ebuf[base[b] + lp] = (src[i] << BSH) | (d & (SZB - 1));
    }
}

// ---------------- pass D: per-bucket finalize: deg->dinv, offsets, sorted ssrc ----------------
__global__ __launch_bounds__(256) void bucket_finalize(const int* __restrict__ bbase,
                                                       const int* __restrict__ ebuf,
                                                       int N, int E,
                                                       int* __restrict__ off,
                                                       float* __restrict__ dinv,
                                                       int* __restrict__ ssrc) {
    __shared__ int deg[SZB];
    __shared__ int scn[SZB];
    __shared__ int cur[SZB];
    __shared__ int wsum[256];
    __shared__ int sstage[CAP];
    const int b = blockIdx.x;
    const int s0 = bbase[b], s1 = bbase[b + 1];
    const int cnt = s1 - s0;
    const int n0 = b << BSH;
    const int nn = min(SZB, N - n0);
    const int t = threadIdx.x;
    deg[t] = 0; deg[t + 256] = 0;
    __syncthreads();
    for (int i = s0 + t; i < s1; i += 256)
        atomicAdd(&deg[ebuf[i] & (SZB - 1)], 1);
    __syncthreads();
    int a0 = deg[2 * t], a1 = deg[2 * t + 1];
    int v = a0 + a1;
    wsum[t] = v;
    __syncthreads();
    for (int o = 1; o < 256; o <<= 1) {
        int p = (t >= o) ? wsum[t - o] : 0;
        __syncthreads();
        wsum[t] += p;
        __syncthreads();
    }
    int ex = wsum[t] - v;
    scn[2 * t] = ex;       scn[2 * t + 1] = ex + a0;
    cur[2 * t] = ex;       cur[2 * t + 1] = ex + a0;
    __syncthreads();
    for (int i = t; i < nn; i += 256) {
        off[n0 + i]  = s0 + scn[i];
        dinv[n0 + i] = rsqrtf((float)(deg[i] + 1));
    }
    if (b == 0 && t == 0) off[N] = E;
    if (cnt <= CAP) {
        for (int i = s0 + t; i < s1; i += 256) {
            int p = ebuf[i];
            int lp = atomicAdd(&cur[p & (SZB - 1)], 1);
            sstage[lp] = p >> BSH;
        }
        __syncthreads();
        for (int i = t; i < cnt; i += 256) ssrc[s0 + i] = sstage[i];
    } else {               // correctness fallback (statistically unreachable)
        for (int i = s0 + t; i < s1; i += 256) {
            int p = ebuf[i];
            int lp = atomicAdd(&cur[p & (SZB - 1)], 1);
            ssrc[s0 + lp] = p >> BSH;
        }
    }
}

// ---------------- register-tiled GEMM: H = (X@W) * dinv[row] ----------------
// 256-row x NC tile per 256-thread block; thread computes 8 rows x CPT cols.
// X tile staged TRANSPOSED in LDS (LD=260 keeps 16B alignment, transpose
// writes are <=2-way bank conflicts = free); K chunked at KC=16.
template<int K, int NC>
__global__ __launch_bounds__(256) void gemm_reg(const float* __restrict__ X,
                                                const float* __restrict__ W,
                                                const float* __restrict__ dinv,
                                                float* __restrict__ H, int nrows) {
    constexpr int KC  = 16;
    constexpr int LD  = 260;          // 256 + 4 pad: conflict-free transpose, 16B-aligned rows
    constexpr int CPT = NC / 8;       // 8 (L1) or 5 (L2)
    __shared__ float xT[KC][LD];
    __shared__ float ws[KC][NC];
    const int t    = threadIdx.x;
    const int row0 = blockIdx.x * 256;
    const int rowg = t >> 3;          // 32 groups of 8 rows
    const int colg = t & 7;           // 8 groups of CPT cols
    const int r0   = rowg * 8;
    const int c0   = colg * CPT;

    float acc[8][CPT];
#pragma unroll
    for (int r = 0; r < 8; ++r)
#pragma unroll
        for (int j = 0; j < CPT; ++j) acc[r][j] = 0.f;

    for (int kc = 0; kc < K; kc += KC) {
        // stage W chunk (contiguous KC*NC floats)
        for (int i = t; i < KC * NC / 4; i += 256)
            ((float4*)&ws[0][0])[i] = ((const float4*)W)[(kc * NC) / 4 + i];
        // stage X chunk transposed: 256 rows x KC
#pragma unroll
        for (int ii = 0; ii < 4; ++ii) {
            int idx = t + ii * 256;
            int row = idx >> 2, k4 = idx & 3;
            int gr = row0 + row;
            float4 v = make_float4(0.f, 0.f, 0.f, 0.f);
            if (gr < nrows) v = *(const float4*)&X[(long long)gr * K + kc + k4 * 4];
            xT[k4 * 4 + 0][row] = v.x;
            xT[k4 * 4 + 1][row] = v.y;
            xT[k4 * 4 + 2][row] = v.z;
            xT[k4 * 4 + 3][row] = v.w;
        }
        __syncthreads();
#pragma unroll
        for (int k = 0; k < KC; ++k) {
            float xr[8];
            *(float4*)&xr[0] = *(const float4*)&xT[k][r0];
            *(float4*)&xr[4] = *(const float4*)&xT[k][r0 + 4];
            float wr[CPT];
            if constexpr (CPT == 8) {
                *(float4*)&wr[0] = *(const float4*)&ws[k][c0];
                *(float4*)&wr[4] = *(const float4*)&ws[k][c0 + 4];
            } else {
#pragma unroll
                for (int j = 0; j < CPT; ++j) wr[j] = ws[k][c0 + j];
            }
#pragma unroll
            for (int r = 0; r < 8; ++r)
#pragma unroll
                for (int j = 0; j < CPT; ++j) acc[r][j] += xr[r] * wr[j];
        }
        __syncthreads();
    }
    // epilogue: scale by dinv[row], store
#pragma unroll
    for (int r = 0; r < 8; ++r) {
        int gr = row0 + r0 + r;
        if (gr < nrows) {
            float dv = dinv[gr];
            if constexpr (CPT == 8) {
                float4 o0 = make_float4(acc[r][0] * dv, acc[r][1] * dv, acc[r][2] * dv, acc[r][3] * dv);
                float4 o1 = make_float4(acc[r][4] * dv, acc[r][5] * dv, acc[r][6] * dv, acc[r][7] * dv);
                *(float4*)&H[(long long)gr * NC + c0]     = o0;
                *(float4*)&H[(long long)gr * NC + c0 + 4] = o1;
            } else {
#pragma unroll
                for (int j = 0; j < CPT; ++j) H[(long long)gr * NC + c0 + j] = acc[r][j] * dv;
            }
        }
    }
}

// ---------------- layer-1 aggregation (F=64) + bias + ReLU ----------------
__global__ __launch_bounds__(256) void agg_relu(const int* __restrict__ off,
                                                const int* __restrict__ ssrc,
                                                const float* __restrict__ dinv,
                                                const float* __restrict__ hs,
                                                const float* __restrict__ bias,
                                                float* __restrict__ outp, int N) {
    int node = blockIdx.x * 4 + (threadIdx.x >> 6);
    int lane = threadIdx.x & 63;
    if (node >= N) return;
    int start = off[node], end = off[node + 1];
    float acc = 0.f;
    for (int j = start; j < end; j += 64) {
        int idx = j + lane;
        int sidx = (idx < end) ? ssrc[idx] : 0;
        int cnt = min(64, end - j);
        int t = 0;
        for (; t + 3 < cnt; t += 4) {
            int s0 = __shfl(sidx, t);
            int s1 = __shfl(sidx, t + 1);
            int s2 = __shfl(sidx, t + 2);
            int s3 = __shfl(sidx, t + 3);
            acc += hs[(long long)s0 * 64 + lane];
            acc += hs[(long long)s1 * 64 + lane];
            acc += hs[(long long)s2 * 64 + lane];
            acc += hs[(long long)s3 * 64 + lane];
        }
        for (; t < cnt; ++t) {
            int s = __shfl(sidx, t);
            acc += hs[(long long)s * 64 + lane];
        }
    }
    float dd = dinv[node];
    acc = (acc + hs[(long long)node * 64 + lane]) * dd + bias[lane];
    outp[(long long)node * 64 + lane] = fmaxf(acc, 0.f);
}

// ---------------- layer-2 aggregation (F=40) + bias + log_softmax ----------------
__global__ __launch_bounds__(256) void agg_lsm(const int* __restrict__ off,
                                               const int* __restrict__ ssrc,
                                               const float* __restrict__ dinv,
                                               const float* __restrict__ hs,
                                               const float* __restrict__ bias,
                                               float* __restrict__ outp, int N) {
    int node = blockIdx.x * 4 + (threadIdx.x >> 6);
    int lane = threadIdx.x & 63;
    if (node >= N) return;
    int start = off[node], end = off[node + 1];
    float acc = 0.f;
    bool act = lane < N_OUT;
    for (int j = start; j < end; j += 64) {
        int idx = j + lane;
        int sidx = (idx < end) ? ssrc[idx] : 0;
        int cnt = min(64, end - j);
        int t = 0;
        for (; t + 3 < cnt; t += 4) {
            int s0 = __shfl(sidx, t);
            int s1 = __shfl(sidx, t + 1);
            int s2 = __shfl(sidx, t + 2);
            int s3 = __shfl(sidx, t + 3);
            if (act) {
                acc += hs[(long long)s0 * N_OUT + lane];
                acc += hs[(long long)s1 * N_OUT + lane];
                acc += hs[(long long)s2 * N_OUT + lane];
                acc += hs[(long long)s3 * N_OUT + lane];
            }
        }
        for (; t < cnt; ++t) {
            int s = __shfl(sidx, t);
            if (act) acc += hs[(long long)s * N_OUT + lane];
        }
    }
    float val = 0.f, m = -INFINITY;
    if (act) {
        float dd = dinv[node];
        val = (acc + hs[(long long)node * N_OUT + lane]) * dd + bias[lane];
        m = val;
    }
#pragma unroll
    for (int o = 32; o; o >>= 1) m = fmaxf(m, __shfl_xor(m, o));
    float ex = act ? expf(val - m) : 0.f;
#pragma unroll
    for (int o = 32; o; o >>= 1) ex += __shfl_xor(ex, o);
    if (act) outp[(long long)node * N_OUT + lane] = (val - m) - logf(ex);
}

extern "C" void kernel_launch(void* const* d_in, const int* in_sizes, int n_in,
                              void* d_out, int out_size, void* d_ws, size_t ws_size,
                              hipStream_t stream) {
    const float* x  = (const float*)d_in[0];
    const int*   ei = (const int*)d_in[1];
    const float* W1 = (const float*)d_in[2];
    const float* b1 = (const float*)d_in[3];
    const float* W2 = (const float*)d_in[4];
    const float* b2 = (const float*)d_in[5];
    float* out = (float*)d_out;

    const int N = in_sizes[0] / N_IN;     // 100000
    const int E = in_sizes[1] / 2;        // 1600000
    const int* src = ei;
    const int* dst = ei + E;
    const int NBK = (N + SZB - 1) >> BSH; // 196

    // workspace layout
    int*   bcnt  = (int*)d_ws;                          // MAXBK
    int*   bbase = bcnt + MAXBK;                        // MAXBK+1
    int*   bcur  = bbase + MAXBK + 1;                   // MAXBK
    int*   off   = bcur + MAXBK;                        // N+1
    float* dinv  = (float*)(off + N + 1);               // N
    int*   ssrc  = (int*)(dinv + N);                    // E
    float* bufA  = (float*)(ssrc + E);                  // N*64
    float* bufB  = bufA + (size_t)N * N_HID;            // N*64
    int*   ebuf  = (int*)bufB;                          // E ints, aliases bufB (dead by then)

    hipMemsetAsync(bcnt, 0, MAXBK * sizeof(int), stream);

    // CSR build (bucketed counting sort)
    bucket_hist<<<256, 256, 0, stream>>>(dst, E, NBK, bcnt);
    bucket_scan<<<1, 256, 0, stream>>>(bcnt, NBK, E, bbase, bcur);
    bucket_scatter<<<512, 256, 0, stream>>>(src, dst, E, NBK, bcur, ebuf);
    bucket_finalize<<<NBK, 256, 0, stream>>>(bbase, ebuf, N, E, off, dinv, ssrc);

    // layer 1: hs1 = (x@W1)*dinv  -> agg+bias+relu -> bufB
    gemm_reg<N_IN, N_HID><<<(N + 255) / 256, 256, 0, stream>>>(x, W1, dinv, bufA, N);
    agg_relu<<<(N + 3) / 4, 256, 0, stream>>>(off, ssrc, dinv, bufA, b1, bufB, N);

    // layer 2: hs2 = (a1@W2)*dinv -> agg+bias+log_softmax -> out
    gemm_reg<N_HID, N_OUT><<<(N + 255) / 256, 256, 0, stream>>>(bufB, W2, dinv, bufA, N);
    agg_lsm<<<(N + 3) / 4, 256, 0, stream>>>(off, ssrc, dinv, bufA, b2, out, N);
}

// Round 5
// 263.918 us; speedup vs baseline: 3.1562x; 1.0186x over previous
//
#include <hip/hip_runtime.h>
#include <math.h>

#define N_IN  128
#define N_HID 64
#define N_OUT 40

#define BSH   9
#define SZB   512          // nodes per bucket
#define MAXBK 256          // >= NBK (N<=131072)
#define CAP   9216         // LDS staging capacity per bucket (mean 8192, sigma 90)

// ---------------- pass A: global bucket histogram ----------------
__global__ __launch_bounds__(256) void bucket_hist(const int* __restrict__ dst, int E, int NBK,
                                                   int* __restrict__ bcnt) {
    __shared__ int h[MAXBK];
    for (int i = threadIdx.x; i < MAXBK; i += 256) h[i] = 0;
    __syncthreads();
    for (long long i = (long long)blockIdx.x * 256 + threadIdx.x; i < E;
         i += (long long)gridDim.x * 256)
        atomicAdd(&h[dst[i] >> BSH], 1);
    __syncthreads();
    for (int i = threadIdx.x; i < NBK; i += 256)
        if (h[i]) atomicAdd(&bcnt[i], h[i]);
}

// ---------------- pass B: scan bucket counts ----------------
__global__ __launch_bounds__(256) void bucket_scan(const int* __restrict__ bcnt, int NBK, int E,
                                                   int* __restrict__ bbase, int* __restrict__ bcur) {
    __shared__ int lds[MAXBK];
    int t = threadIdx.x;
    int v = (t < NBK) ? bcnt[t] : 0;
    lds[t] = v;
    __syncthreads();
    for (int o = 1; o < 256; o <<= 1) {
        int p = (t >= o) ? lds[t - o] : 0;
        __syncthreads();
        lds[t] += p;
        __syncthreads();
    }
    int ex = lds[t] - v;
    if (t < NBK) { bbase[t] = ex; bcur[t] = ex; }
    if (t == 0) bbase[NBK] = E;
}

// ---------------- pass C: scatter edges into bucket regions (packed) ----------------
__global__ __launch_bounds__(256) void bucket_scatter(const int* __restrict__ src,
                                                      const int* __restrict__ dst,
                                                      int E, int NBK,
                                                      int* __restrict__ bcur,
                                                      int* __restrict__ ebuf) {
    __shared__ int h[MAXBK];
    __shared__ int base[MAXBK];
    int chunk = (E + gridDim.x - 1) / gridDim.x;
    int s = blockIdx.x * chunk;
    int e = min(E, s + chunk);
    for (int i = threadIdx.x; i < MAXBK; i += 256) h[i] = 0;
    __syncthreads();
    for (int i = s + threadIdx.x; i < e; i += 256)
        atomicAdd(&h[dst[i] >> BSH], 1);
    __syncthreads();
    for (int i = threadIdx.x; i < NBK; i += 256) {
        int c = h[i];
        base[i] = c ? atomicAdd(&bcur[i], c) : 0;
    }
    __syncthreads();
    for (int i = threadIdx.x; i < MAXBK; i += 256) h[i] = 0;
    __syncthreads();
    for (int i = s + threadIdx.x; i < e; i += 256) {
        int d = dst[i];
        int b = d >> BSH;
        int lp = atomicAdd(&h[b], 1);
        ebuf[base[b] + lp] = (src[i] << BSH) | (d & (SZB - 1));
    }
}

// ---------------- pass D: per-bucket finalize: deg->dinv, offsets, sorted ssrc ----------------
__global__ __launch_bounds__(256) void bucket_finalize(const int* __restrict__ bbase,
                                                       const int* __restrict__ ebuf,
                                                       int N, int E,
                                                       int* __restrict__ off,
                                                       float* __restrict__ dinv,
                                                       int* __restrict__ ssrc) {
    __shared__ int deg[SZB];
    __shared__ int scn[SZB];
    __shared__ int cur[SZB];
    __shared__ int wsum[256];
    __shared__ int sstage[CAP];
    const int b = blockIdx.x;
    const int s0 = bbase[b], s1 = bbase[b + 1];
    const int cnt = s1 - s0;
    const int n0 = b << BSH;
    const int nn = min(SZB, N - n0);
    const int t = threadIdx.x;
    deg[t] = 0; deg[t + 256] = 0;
    __syncthreads();
    for (int i = s0 + t; i < s1; i += 256)
        atomicAdd(&deg[ebuf[i] & (SZB - 1)], 1);
    __syncthreads();
    int a0 = deg[2 * t], a1 = deg[2 * t + 1];
    int v = a0 + a1;
    wsum[t] = v;
    __syncthreads();
    for (int o = 1; o < 256; o <<= 1) {
        int p = (t >= o) ? wsum[t - o] : 0;
        __syncthreads();
        wsum[t] += p;
        __syncthreads();
    }
    int ex = wsum[t] - v;
    scn[2 * t] = ex;       scn[2 * t + 1] = ex + a0;
    cur[2 * t] = ex;       cur[2 * t + 1] = ex + a0;
    __syncthreads();
    for (int i = t; i < nn; i += 256) {
        off[n0 + i]  = s0 + scn[i];
        dinv[n0 + i] = rsqrtf((float)(deg[i] + 1));
    }
    if (b == 0 && t == 0) off[N] = E;
    if (cnt <= CAP) {
        for (int i = s0 + t; i < s1; i += 256) {
            int p = ebuf[i];
            int lp = atomicAdd(&cur[p & (SZB - 1)], 1);
            sstage[lp] = p >> BSH;
        }
        __syncthreads();
        for (int i = t; i < cnt; i += 256) ssrc[s0 + i] = sstage[i];
    } else {               // correctness fallback (statistically unreachable)
        for (int i = s0 + t; i < s1; i += 256) {
            int p = ebuf[i];
            int lp = atomicAdd(&cur[p & (SZB - 1)], 1);
            ssrc[s0 + lp] = p >> BSH;
        }
    }
}

// ---------------- bf16 helpers (RNE) ----------------
__device__ __forceinline__ unsigned short bf16_of(float x) {
    unsigned b = __float_as_uint(x);
    return (unsigned short)((b + 0x7fffu + ((b >> 16) & 1u)) >> 16);
}
__device__ __forceinline__ unsigned pack_bf16(float lo, float hi) {
    unsigned bl = __float_as_uint(lo), bh = __float_as_uint(hi);
    bl = (bl + 0x7fffu + ((bl >> 16) & 1u)) >> 16;
    bh = (bh + 0x7fffu + ((bh >> 16) & 1u)) & 0xffff0000u;
    return bl | bh;
}

// ---------------- register-tiled GEMM: T = bf16( (X@W) * dinv[row] ) ----------------
// 256-row x NC tile per 256-thread block; thread computes 8 rows x CPT cols.
template<int K, int NC>
__global__ __launch_bounds__(256) void gemm_reg(const float* __restrict__ X,
                                                const float* __restrict__ W,
                                                const float* __restrict__ dinv,
                                                unsigned* __restrict__ T, int nrows) {
    constexpr int KC  = 16;
    constexpr int LD  = 260;
    constexpr int CPT = NC / 8;       // 8 (L1) or 5 (L2)
    __shared__ float xT[KC][LD];
    __shared__ float ws[KC][NC];
    const int t    = threadIdx.x;
    const int row0 = blockIdx.x * 256;
    const int rowg = t >> 3;
    const int colg = t & 7;
    const int r0   = rowg * 8;
    const int c0   = colg * CPT;

    float acc[8][CPT];
#pragma unroll
    for (int r = 0; r < 8; ++r)
#pragma unroll
        for (int j = 0; j < CPT; ++j) acc[r][j] = 0.f;

    for (int kc = 0; kc < K; kc += KC) {
        for (int i = t; i < KC * NC / 4; i += 256)
            ((float4*)&ws[0][0])[i] = ((const float4*)W)[(kc * NC) / 4 + i];
#pragma unroll
        for (int ii = 0; ii < 4; ++ii) {
            int idx = t + ii * 256;
            int row = idx >> 2, k4 = idx & 3;
            int gr = row0 + row;
            float4 v = make_float4(0.f, 0.f, 0.f, 0.f);
            if (gr < nrows) v = *(const float4*)&X[(long long)gr * K + kc + k4 * 4];
            xT[k4 * 4 + 0][row] = v.x;
            xT[k4 * 4 + 1][row] = v.y;
            xT[k4 * 4 + 2][row] = v.z;
            xT[k4 * 4 + 3][row] = v.w;
        }
        __syncthreads();
#pragma unroll
        for (int k = 0; k < KC; ++k) {
            float xr[8];
            *(float4*)&xr[0] = *(const float4*)&xT[k][r0];
            *(float4*)&xr[4] = *(const float4*)&xT[k][r0 + 4];
            float wr[CPT];
            if constexpr (CPT == 8) {
                *(float4*)&wr[0] = *(const float4*)&ws[k][c0];
                *(float4*)&wr[4] = *(const float4*)&ws[k][c0 + 4];
            } else {
#pragma unroll
                for (int j = 0; j < CPT; ++j) wr[j] = ws[k][c0 + j];
            }
#pragma unroll
            for (int r = 0; r < 8; ++r)
#pragma unroll
                for (int j = 0; j < CPT; ++j) acc[r][j] += xr[r] * wr[j];
        }
        __syncthreads();
    }
#pragma unroll
    for (int r = 0; r < 8; ++r) {
        int gr = row0 + r0 + r;
        if (gr < nrows) {
            float dv = dinv[gr];
            if constexpr (CPT == 8) {
                uint4 o;
                o.x = pack_bf16(acc[r][0] * dv, acc[r][1] * dv);
                o.y = pack_bf16(acc[r][2] * dv, acc[r][3] * dv);
                o.z = pack_bf16(acc[r][4] * dv, acc[r][5] * dv);
                o.w = pack_bf16(acc[r][6] * dv, acc[r][7] * dv);
                *(uint4*)&T[(long long)gr * (NC / 2) + colg * 4] = o;
            } else {
                unsigned short* row = (unsigned short*)&T[(long long)gr * (NC / 2)];
#pragma unroll
                for (int j = 0; j < CPT; ++j) row[c0 + j] = bf16_of(acc[r][j] * dv);
            }
        }
    }
}

// ---------------- layer-1 aggregation (F=64, bf16 table) + bias + ReLU ----------------
// two edges per wave: half h=lane>>5 handles edge t+h; lane ln=lane&31 owns feats (2ln,2ln+1)
__global__ __launch_bounds__(256) void agg_relu_b16(const int* __restrict__ off,
                                                    const int* __restrict__ ssrc,
                                                    const float* __restrict__ dinv,
                                                    const unsigned* __restrict__ tab,  // N x 32
                                                    const float* __restrict__ bias,
                                                    float* __restrict__ outp, int N) {
    int node = blockIdx.x * 4 + (threadIdx.x >> 6);
    int lane = threadIdx.x & 63;
    if (node >= N) return;
    const int h  = lane >> 5;
    const int ln = lane & 31;
    int start = off[node], end = off[node + 1];
    float a0 = 0.f, a1 = 0.f;
    for (int j = start; j < end; j += 64) {
        int idx = j + lane;
        int sidx = (idx < end) ? ssrc[idx] : 0;
        int cnt = min(64, end - j);
        for (int t = 0; t < cnt; t += 2) {
            int s = __shfl(sidx, t + h);
            if (t + h < cnt) {
                unsigned u = tab[(long long)s * 32 + ln];
                a0 += __uint_as_float(u << 16);
                a1 += __uint_as_float(u & 0xffff0000u);
            }
        }
    }
    a0 += __shfl_xor(a0, 32);
    a1 += __shfl_xor(a1, 32);
    unsigned us = tab[(long long)node * 32 + ln];     // self-loop term
    a0 += __uint_as_float(us << 16);
    a1 += __uint_as_float(us & 0xffff0000u);
    float dd = dinv[node];
    a0 = fmaxf(a0 * dd + bias[2 * ln],     0.f);
    a1 = fmaxf(a1 * dd + bias[2 * ln + 1], 0.f);
    if (h == 0)
        *(float2*)&outp[(long long)node * 64 + 2 * ln] = make_float2(a0, a1);
}

// ---------------- layer-2 aggregation (F=40, bf16 table) + bias + log_softmax ----------------
__global__ __launch_bounds__(256) void agg_lsm_b16(const int* __restrict__ off,
                                                   const int* __restrict__ ssrc,
                                                   const float* __restrict__ dinv,
                                                   const unsigned* __restrict__ tab,  // N x 20
                                                   const float* __restrict__ bias,
                                                   float* __restrict__ outp, int N) {
    int node = blockIdx.x * 4 + (threadIdx.x >> 6);
    int lane = threadIdx.x & 63;
    if (node >= N) return;
    const int h   = lane >> 5;
    const int ln  = lane & 31;
    const bool act = ln < 20;
    int start = off[node], end = off[node + 1];
    float a0 = 0.f, a1 = 0.f;
    for (int j = start; j < end; j += 64) {
        int idx = j + lane;
        int sidx = (idx < end) ? ssrc[idx] : 0;
        int cnt = min(64, end - j);
        for (int t = 0; t < cnt; t += 2) {
            int s = __shfl(sidx, t + h);
            if (act && t + h < cnt) {
                unsigned u = tab[(long long)s * 20 + ln];
                a0 += __uint_as_float(u << 16);
                a1 += __uint_as_float(u & 0xffff0000u);
            }
        }
    }
    a0 += __shfl_xor(a0, 32);
    a1 += __shfl_xor(a1, 32);
    float v0 = 0.f, v1 = 0.f, m = -INFINITY;
    if (act) {
        unsigned us = tab[(long long)node * 20 + ln];
        a0 += __uint_as_float(us << 16);
        a1 += __uint_as_float(us & 0xffff0000u);
        float dd = dinv[node];
        v0 = a0 * dd + bias[2 * ln];
        v1 = a1 * dd + bias[2 * ln + 1];
        m = fmaxf(v0, v1);
    }
#pragma unroll
    for (int o = 16; o; o >>= 1) m = fmaxf(m, __shfl_xor(m, o));
    float ex = act ? (__expf(v0 - m) + __expf(v1 - m)) : 0.f;
#pragma unroll
    for (int o = 16; o; o >>= 1) ex += __shfl_xor(ex, o);
    if (act && h == 0) {
        float lse = logf(ex);
        *(float2*)&outp[(long long)node * 40 + 2 * ln] =
            make_float2((v0 - m) - lse, (v1 - m) - lse);
    }
}

extern "C" void kernel_launch(void* const* d_in, const int* in_sizes, int n_in,
                              void* d_out, int out_size, void* d_ws, size_t ws_size,
                              hipStream_t stream) {
    const float* x  = (const float*)d_in[0];
    const int*   ei = (const int*)d_in[1];
    const float* W1 = (const float*)d_in[2];
    const float* b1 = (const float*)d_in[3];
    const float* W2 = (const float*)d_in[4];
    const float* b2 = (const float*)d_in[5];
    float* out = (float*)d_out;

    const int N = in_sizes[0] / N_IN;     // 100000
    const int E = in_sizes[1] / 2;        // 1600000
    const int* src = ei;
    const int* dst = ei + E;
    const int NBK = (N + SZB - 1) >> BSH; // 196

    // workspace layout (4B units)
    int*      bcnt  = (int*)d_ws;                       // MAXBK
    int*      bbase = bcnt + MAXBK;                     // MAXBK+1
    int*      bcur  = bbase + MAXBK + 1;                // MAXBK
    int*      off   = bcur + MAXBK;                     // N+1
    float*    dinv  = (float*)(off + N + 1);            // N
    int*      ssrc  = (int*)(dinv + N);                 // E
    unsigned* tabA  = (unsigned*)(ssrc + E);            // N*32 (hs1 bf16)
    unsigned* tabB  = tabA + (size_t)N * 32;            // N*20 (hs2 bf16)
    float*    bufB  = (float*)(tabB + (size_t)N * 20);  // N*64 (a1 fp32)
    int*      ebuf  = (int*)bufB;                       // E ints, aliases bufB (dead by then)

    hipMemsetAsync(bcnt, 0, MAXBK * sizeof(int), stream);

    // CSR build (bucketed counting sort)
    bucket_hist<<<256, 256, 0, stream>>>(dst, E, NBK, bcnt);
    bucket_scan<<<1, 256, 0, stream>>>(bcnt, NBK, E, bbase, bcur);
    bucket_scatter<<<512, 256, 0, stream>>>(src, dst, E, NBK, bcur, ebuf);
    bucket_finalize<<<NBK, 256, 0, stream>>>(bbase, ebuf, N, E, off, dinv, ssrc);

    // layer 1: tabA = bf16((x@W1)*dinv) -> agg+bias+relu -> bufB (fp32)
    gemm_reg<N_IN, N_HID><<<(N + 255) / 256, 256, 0, stream>>>(x, W1, dinv, tabA, N);
    agg_relu_b16<<<(N + 3) / 4, 256, 0, stream>>>(off, ssrc, dinv, tabA, b1, bufB, N);

    // layer 2: tabB = bf16((a1@W2)*dinv) -> agg+bias+log_softmax -> out
    gemm_reg<N_HID, N_OUT><<<(N + 255) / 256, 256, 0, stream>>>(bufB, W2, dinv, tabB, N);
    agg_lsm_b16<<<(N + 3) / 4, 256, 0, stream>>>(off, ssrc, dinv, tabB, b2, out, N);
}